// Round 6
// baseline (466.116 us; speedup 1.0000x reference)
//
#include <hip/hip_runtime.h>

// ---------------------------------------------------------------------------
// Earth padding of 5 strips (B=1, C=256) + edge-row cross-strip convs.
// Outputs (concatenated): (256,34,364)(256,64,724)(256,184,1444)(256,64,724)(256,34,364)
//
// Round-6: SPLIT for per-phase rocprof visibility (ablation round):
//   k1 transpose_all : wt[ic][k][oc] lane-coalesced weight tables (5120 blk)
//   k2 conv_kernel   : 1080 blocks, one conv unit each; rolled outer loop
//                      (#pragma unroll 1, small code) + explicit wA/wB ping-pong
//   k3 copy_kernel   : 2048 persistent blocks, static row split, manual
//                      2-deep load clustering (beats in-order vmcnt hazard)
// ---------------------------------------------------------------------------

struct ConvJob {
  const float* x; const float* wt; const float* bias; float* out;
  int Hin, Win, r0, Hout, Wcore, h0, blk_start;
};
struct ConvParams { ConvJob j[8]; };

struct CopyParams {
  const float* in0; const float* in1; const float* in2; const float* in3; const float* in4;
  float* o0; float* o1; float* o2; float* o3; float* o4;
};

struct WTParams { const float* src[4]; float* dst[4]; };

// --- weight transpose: dst[(ic*5+k)*256 + oc] ---
// which 0,1: src is wi [ic][oc][1][k] ; which 2,3: src is wo [oc][ic][1][k]
__global__ __launch_bounds__(256) void transpose_all_kernel(WTParams p) {
  int b = blockIdx.x;                       // 5120 blocks = 4 * 1280
  int which = b / 1280;
  int idx = (b - which * 1280) * 256 + threadIdx.x;
  int oc = idx & 255;
  int q = idx >> 8;
  int k = q % 5;
  int ic = q / 5;
  const float* s = p.src[which];
  float v = (which < 2) ? s[(ic * 256 + oc) * 5 + k] : s[(oc * 256 + ic) * 5 + k];
  p.dst[which][idx] = v;
}

// ---------------------------------------------------------------------------
// Conv kernel
// ---------------------------------------------------------------------------

// FMA micro-step: acc[sel] += w[k..] dot xq, for the valid (sel,k) pairs of
// column cc. NOUT=8 (fwd, k=cc-2i) or 16 (convT, k=ml+4-2cc).
template <int NOUT, int NCC>
__device__ __forceinline__ void fma_cols(float* acc, const float* w, const float* xsrow,
                                         int ic0) {
#pragma unroll
  for (int cc = 0; cc < NCC; ++cc) {
    float4 xq = *(const float4*)&xsrow[cc * 256 + ic0];
#pragma unroll
    for (int i = 0; i < NOUT; ++i) {
      int k = (NOUT == 8) ? (cc - 2 * i) : (i + 4 - 2 * cc);
      if (k >= 0 && k < 5)
        acc[i] += w[k] * xq.x + w[5 + k] * xq.y + w[10 + k] * xq.z + w[15 + k] * xq.w;
    }
  }
}

__device__ __forceinline__ void wload(float* wbuf, const float* wt, int ic) {
#pragma unroll
  for (int e = 0; e < 20; ++e) wbuf[e] = wt[(size_t)(ic * 5 + e) * 256];
}

template <int NOUT, int NCC>
__device__ __forceinline__ void conv_unit(const ConvJob jb, int local, int t, float* xs,
                                          float bv) {
  int tile = local >> 1;
  int r = local & 1;
  const int Win = jb.Win;
  const float* xrow = jb.x + ((size_t)(t * jb.Hin + jb.r0 + r)) * Win;
  const float* wt = jb.wt + t;              // wt[(ic*5+k)*256 + t], lane-coalesced
  const int Wop = jb.Wcore + 4;
  float* orow = jb.out + ((size_t)(t * jb.Hout + jb.h0 + r)) * Wop;

  // stage X columns into LDS
  int base0, ncc;
  if (NOUT == 8) { base0 = 2 * (tile * 8) - 2; ncc = 19; }
  else           { base0 = (tile * 16 >> 1) - 1; ncc = 10; }
#pragma unroll
  for (int cc = 0; cc < NCC; ++cc) {
    int col = base0 + cc;
    col += (col < 0) ? Win : 0;
    col -= (col >= Win) ? Win : 0;
    xs[cc * 256 + t] = xrow[col];
  }
  __syncthreads();

  float acc[NOUT];
#pragma unroll
  for (int i = 0; i < NOUT; ++i) acc[i] = bv;

  float wA[20], wB[20];
  wload(wA, wt, 0);
#pragma unroll 1
  for (int ic0 = 0; ic0 < 256; ic0 += 8) {
    wload(wB, wt, ic0 + 4);                 // prefetch odd chunk
    fma_cols<NOUT, NCC>(acc, wA, xs, ic0);  // compute even chunk
    if (ic0 + 8 < 256) wload(wA, wt, ic0 + 8);  // prefetch next even
    fma_cols<NOUT, NCC>(acc, wB, xs, ic0 + 4);  // compute odd chunk
  }

  int g0 = (NOUT == 8) ? tile * 8 : tile * 16;
#pragma unroll
  for (int i = 0; i < NOUT; ++i) {
    int g = g0 + i;
    float vv = acc[i];
    orow[2 + g] = vv;
    if (g < 2) orow[jb.Wcore + 2 + g] = vv;
    if (g >= jb.Wcore - 2) orow[g - (jb.Wcore - 2)] = vv;
  }
}

__global__ __launch_bounds__(256, 4) void conv_kernel(ConvParams p) {
  __shared__ float xs[19 * 256];            // 19.5 KB -> 4 blocks/CU = 78 KB
  int bx = blockIdx.x;
  int t = threadIdx.x;
  if (bx < 540) {
    int ji = (bx >= 450) ? 3 : (bx >= 360) ? 2 : (bx >= 180) ? 1 : 0;
    conv_unit<16, 10>(p.j[ji], bx - p.j[ji].blk_start, t, xs, 0.f);
  } else {
    int u2 = bx;
    int j2 = (u2 >= 990) ? 7 : (u2 >= 900) ? 6 : (u2 >= 720) ? 5 : 4;
    conv_unit<8, 19>(p.j[j2], u2 - p.j[j2].blk_start, t, xs, p.j[j2].bias[t]);
  }
}

// ---------------------------------------------------------------------------
// Copy kernel
// ---------------------------------------------------------------------------

__device__ __forceinline__ float4 pack4(float2 a, float2 b) {
  return make_float4(a.x, a.y, b.x, b.y);
}

// one padded row; manual 2-deep load clustering for MLP
template <int H, int W>
__device__ __forceinline__ void copy_row(const float* __restrict__ in,
                                         float* __restrict__ out, int rl, int lane) {
  constexpr int CORE = W / 4;               // interior float4 columns: 1..CORE-1
  int c = rl / H;                           // constexpr division (magic mul)
  const float* src = in + (size_t)rl * W;
  float* dst = out + (size_t)(rl + c * 4 + 2) * (W + 4);
  int w4 = 1 + lane;
  while (w4 < CORE) {
    int w4b = w4 + 64;
    float2 a0 = *(const float2*)(src + w4 * 4 - 2);
    float2 b0 = *(const float2*)(src + w4 * 4);
    if (w4b < CORE) {
      float2 a1 = *(const float2*)(src + w4b * 4 - 2);
      float2 b1 = *(const float2*)(src + w4b * 4);
      *(float4*)(dst + w4 * 4) = pack4(a0, b0);
      *(float4*)(dst + w4b * 4) = pack4(a1, b1);
    } else {
      *(float4*)(dst + w4 * 4) = pack4(a0, b0);
    }
    w4 += 128;
  }
  if (lane == 0) {
    // dst[0..3] == dst[W..W+3] == {x[W-2], x[W-1], x[0], x[1]}
    float2 E = *(const float2*)(src + W - 2);
    float2 F = *(const float2*)(src);
    float4 v = pack4(E, F);
    *(float4*)(dst) = v;
    *(float4*)(dst + W) = v;
  }
}

__device__ __forceinline__ void zero_row(const CopyParams& p, int z, int lane) {
  int strip = z >> 9, cr = z & 511, c = cr >> 1, r = cr & 1;
  float* dst = strip ? p.o4 + (size_t)(c * 34 + 32 + r) * 364
                     : p.o0 + (size_t)(c * 34 + r) * 364;
  for (int w4 = lane; w4 < 91; w4 += 64)
    *(float4*)(dst + w4 * 4) = make_float4(0.f, 0.f, 0.f, 0.f);
}

// row-job space: [0,46080) s2 | [,61440) s1 | [,76800) s3 | [,84480) s0
//                | [,92160) s4 | [,93184) zero rows
__device__ __forceinline__ void do_row(const CopyParams& p, int gid, int lane) {
  if (gid < 46080)      copy_row<180, 1440>(p.in2, p.o2, gid, lane);
  else if (gid < 61440) copy_row<60, 720>(p.in1, p.o1, gid - 46080, lane);
  else if (gid < 76800) copy_row<60, 720>(p.in3, p.o3, gid - 61440, lane);
  else if (gid < 84480) copy_row<30, 360>(p.in0, p.o0, gid - 76800, lane);
  else if (gid < 92160) copy_row<30, 360>(p.in4, p.o4, gid - 84480, lane);
  else                  zero_row(p, gid - 92160, lane);
}

__global__ __launch_bounds__(256, 8) void copy_kernel(CopyParams p) {
  int wid = blockIdx.x * 4 + (threadIdx.x >> 6);   // 8192 waves
  int lane = threadIdx.x & 63;
  for (int gid = wid; gid < 93184; gid += 8192) do_row(p, gid, lane);
}

extern "C" void kernel_launch(void* const* d_in, const int* in_sizes, int n_in,
                              void* d_out, int out_size, void* d_ws, size_t ws_size,
                              hipStream_t stream) {
  const float* s0 = (const float*)d_in[0];   // (256,30,360)
  const float* s1 = (const float*)d_in[1];   // (256,60,720)
  const float* s2 = (const float*)d_in[2];   // (256,180,1440)
  const float* s3 = (const float*)d_in[3];   // (256,60,720)
  const float* s4 = (const float*)d_in[4];   // (256,30,360)
  const float* wi0 = (const float*)d_in[5];  // (256,256,1,5) [ic][oc][k]
  const float* wi1 = (const float*)d_in[6];
  const float* wo0 = (const float*)d_in[7];  // (256,256,1,5) [oc][ic][k]
  const float* bo0 = (const float*)d_in[8];
  const float* wo1 = (const float*)d_in[9];
  const float* bo1 = (const float*)d_in[10];

  float* out = (float*)d_out;
  float* out0 = out;                 // (256,34,364)
  float* out1 = out + 3168256;       // (256,64,724)
  float* out2 = out + 15030272;      // (256,184,1444)
  float* out3 = out + 83048448;      // (256,64,724)
  float* out4 = out + 94910464;      // (256,34,364)

  // workspace: 4 transposed weight tables [ic][k][oc]
  float* wt0 = (float*)d_ws;
  float* wt1 = wt0 + 327680;
  float* wt2 = wt1 + 327680;
  float* wt3 = wt2 + 327680;

  WTParams wp;
  wp.src[0] = wi0; wp.src[1] = wi1; wp.src[2] = wo0; wp.src[3] = wo1;
  wp.dst[0] = wt0; wp.dst[1] = wt1; wp.dst[2] = wt2; wp.dst[3] = wt3;
  transpose_all_kernel<<<5120, 256, 0, stream>>>(wp);

  ConvParams cp;
  //           x    wt   bias    out   Hin  Win   r0  Hout Wcore h0  blk_start
  cp.j[0] = {s1, wt0, nullptr, out2,  60,  720,  58, 184, 1440,   0,   0}; // convT -> out2 top    (180 units)
  cp.j[1] = {s3, wt0, nullptr, out2,  60,  720,   0, 184, 1440, 182, 180}; // convT -> out2 bottom (180)
  cp.j[2] = {s0, wt1, nullptr, out1,  30,  360,  28,  64,  720,   0, 360}; // convT -> out1 top    ( 90)
  cp.j[3] = {s4, wt1, nullptr, out3,  30,  360,   0,  64,  720,  62, 450}; // convT -> out3 bottom ( 90)
  cp.j[4] = {s2, wt2, bo0,     out1, 180, 1440,   0,  64,  720,  62, 540}; // fwd   -> out1 bottom (180)
  cp.j[5] = {s2, wt2, bo0,     out3, 180, 1440, 178,  64,  720,   0, 720}; // fwd   -> out3 top    (180)
  cp.j[6] = {s1, wt3, bo1,     out0,  60,  720,   0,  34,  360,  32, 900}; // fwd   -> out0 bottom ( 90)
  cp.j[7] = {s3, wt3, bo1,     out4,  60,  720,  58,  34,  360,   0, 990}; // fwd   -> out4 top    ( 90)
  conv_kernel<<<1080, 256, 0, stream>>>(cp);

  CopyParams kp;
  kp.in0 = s0; kp.in1 = s1; kp.in2 = s2; kp.in3 = s3; kp.in4 = s4;
  kp.o0 = out0; kp.o1 = out1; kp.o2 = out2; kp.o3 = out3; kp.o4 = out4;
  copy_kernel<<<2048, 256, 0, stream>>>(kp);
}

// Round 7
// 335.390 us; speedup vs baseline: 1.3898x; 1.3898x over previous
//
#include <hip/hip_runtime.h>

// ---------------------------------------------------------------------------
// Earth padding of 5 strips (B=1, C=256) + edge-row cross-strip convs.
// Outputs (concatenated): (256,34,364)(256,64,724)(256,184,1444)(256,64,724)(256,34,364)
//
// Round-7: same 3-kernel split as round 6 (per-phase visibility), but the
// conv kernel is de-pipelined: single w[20] per 4-ic chunk in a rolled loop.
// Round-6 post-mortem: wA/wB double-buffer (56+ live floats) vs the
// allocator's 64-VGPR choice => scratch spill => 387 MB of HBM write-back.
// Live set now ~50 regs -> no spill; latency hidden by ~4 waves/SIMD TLP.
// ---------------------------------------------------------------------------

struct ConvJob {
  const float* x; const float* wt; const float* bias; float* out;
  int Hin, Win, r0, Hout, Wcore, h0, blk_start;
};
struct ConvParams { ConvJob j[8]; };

struct CopyParams {
  const float* in0; const float* in1; const float* in2; const float* in3; const float* in4;
  float* o0; float* o1; float* o2; float* o3; float* o4;
};

struct WTParams { const float* src[4]; float* dst[4]; };

// --- weight transpose: dst[(ic*5+k)*256 + oc] ---
// which 0,1: src is wi [ic][oc][1][k] ; which 2,3: src is wo [oc][ic][1][k]
__global__ __launch_bounds__(256) void transpose_all_kernel(WTParams p) {
  int b = blockIdx.x;                       // 5120 blocks = 4 * 1280
  int which = b / 1280;
  int idx = (b - which * 1280) * 256 + threadIdx.x;
  int oc = idx & 255;
  int q = idx >> 8;
  int k = q % 5;
  int ic = q / 5;
  const float* s = p.src[which];
  float v = (which < 2) ? s[(ic * 256 + oc) * 5 + k] : s[(oc * 256 + ic) * 5 + k];
  p.dst[which][idx] = v;
}

// ---------------------------------------------------------------------------
// Conv kernel
// ---------------------------------------------------------------------------

// FMA micro-step for one 4-ic chunk: acc[i] += w[k..] dot xq over valid (cc,i).
// NOUT=8 (fwd, k=cc-2i) or 16 (convT, k=i+4-2cc). 40 valid pairs either way.
template <int NOUT, int NCC>
__device__ __forceinline__ void fma_cols(float* acc, const float* w, const float* xsrow,
                                         int ic0) {
#pragma unroll
  for (int cc = 0; cc < NCC; ++cc) {
    float4 xq = *(const float4*)&xsrow[cc * 256 + ic0];
#pragma unroll
    for (int i = 0; i < NOUT; ++i) {
      int k = (NOUT == 8) ? (cc - 2 * i) : (i + 4 - 2 * cc);
      if (k >= 0 && k < 5)
        acc[i] += w[k] * xq.x + w[5 + k] * xq.y + w[10 + k] * xq.z + w[15 + k] * xq.w;
    }
  }
}

template <int NOUT, int NCC>
__device__ __forceinline__ void conv_unit(const ConvJob jb, int local, int t, float* xs,
                                          float bv) {
  int tile = local >> 1;
  int r = local & 1;
  const int Win = jb.Win;
  const float* xrow = jb.x + ((size_t)(t * jb.Hin + jb.r0 + r)) * Win;
  const float* wt = jb.wt + t;              // wt[(ic*5+k)*256 + t], lane-coalesced
  const int Wop = jb.Wcore + 4;
  float* orow = jb.out + ((size_t)(t * jb.Hout + jb.h0 + r)) * Wop;

  // stage X columns into LDS: xs[cc][ic]
  int base0;
  if (NOUT == 8) base0 = 2 * (tile * 8) - 2;     // fwd: cols 2u0-2 .. 2u0+16
  else           base0 = (tile * 16 >> 1) - 1;   // convT: cols m0/2-1 .. m0/2+8
#pragma unroll
  for (int cc = 0; cc < NCC; ++cc) {
    int col = base0 + cc;
    col += (col < 0) ? Win : 0;
    col -= (col >= Win) ? Win : 0;
    xs[cc * 256 + t] = xrow[col];
  }
  __syncthreads();

  float acc[NOUT];
#pragma unroll
  for (int i = 0; i < NOUT; ++i) acc[i] = bv;

#pragma unroll 1
  for (int ic0 = 0; ic0 < 256; ic0 += 4) {
    float w[20];
#pragma unroll
    for (int e = 0; e < 20; ++e) w[e] = wt[(size_t)(ic0 * 5 + e) * 256];
    fma_cols<NOUT, NCC>(acc, w, xs, ic0);
  }

  int g0 = (NOUT == 8) ? tile * 8 : tile * 16;
#pragma unroll
  for (int i = 0; i < NOUT; ++i) {
    int g = g0 + i;
    float vv = acc[i];
    orow[2 + g] = vv;
    if (g < 2) orow[jb.Wcore + 2 + g] = vv;
    if (g >= jb.Wcore - 2) orow[g - (jb.Wcore - 2)] = vv;
  }
}

__global__ __launch_bounds__(256, 4) void conv_kernel(ConvParams p) {
  __shared__ float xs[19 * 256];            // 19.5 KB
  int bx = blockIdx.x;
  int t = threadIdx.x;
  if (bx < 540) {
    int ji = (bx >= 450) ? 3 : (bx >= 360) ? 2 : (bx >= 180) ? 1 : 0;
    conv_unit<16, 10>(p.j[ji], bx - p.j[ji].blk_start, t, xs, 0.f);
  } else {
    int j2 = (bx >= 990) ? 7 : (bx >= 900) ? 6 : (bx >= 720) ? 5 : 4;
    conv_unit<8, 19>(p.j[j2], bx - p.j[j2].blk_start, t, xs, p.j[j2].bias[t]);
  }
}

// ---------------------------------------------------------------------------
// Copy kernel (unchanged from round 6 — measured near HBM ceiling)
// ---------------------------------------------------------------------------

__device__ __forceinline__ float4 pack4(float2 a, float2 b) {
  return make_float4(a.x, a.y, b.x, b.y);
}

template <int H, int W>
__device__ __forceinline__ void copy_row(const float* __restrict__ in,
                                         float* __restrict__ out, int rl, int lane) {
  constexpr int CORE = W / 4;               // interior float4 columns: 1..CORE-1
  int c = rl / H;
  const float* src = in + (size_t)rl * W;
  float* dst = out + (size_t)(rl + c * 4 + 2) * (W + 4);
  int w4 = 1 + lane;
  while (w4 < CORE) {
    int w4b = w4 + 64;
    float2 a0 = *(const float2*)(src + w4 * 4 - 2);
    float2 b0 = *(const float2*)(src + w4 * 4);
    if (w4b < CORE) {
      float2 a1 = *(const float2*)(src + w4b * 4 - 2);
      float2 b1 = *(const float2*)(src + w4b * 4);
      *(float4*)(dst + w4 * 4) = pack4(a0, b0);
      *(float4*)(dst + w4b * 4) = pack4(a1, b1);
    } else {
      *(float4*)(dst + w4 * 4) = pack4(a0, b0);
    }
    w4 += 128;
  }
  if (lane == 0) {
    // dst[0..3] == dst[W..W+3] == {x[W-2], x[W-1], x[0], x[1]}
    float2 E = *(const float2*)(src + W - 2);
    float2 F = *(const float2*)(src);
    float4 v = pack4(E, F);
    *(float4*)(dst) = v;
    *(float4*)(dst + W) = v;
  }
}

__device__ __forceinline__ void zero_row(const CopyParams& p, int z, int lane) {
  int strip = z >> 9, cr = z & 511, c = cr >> 1, r = cr & 1;
  float* dst = strip ? p.o4 + (size_t)(c * 34 + 32 + r) * 364
                     : p.o0 + (size_t)(c * 34 + r) * 364;
  for (int w4 = lane; w4 < 91; w4 += 64)
    *(float4*)(dst + w4 * 4) = make_float4(0.f, 0.f, 0.f, 0.f);
}

// row-job space: [0,46080) s2 | [,61440) s1 | [,76800) s3 | [,84480) s0
//                | [,92160) s4 | [,93184) zero rows
__device__ __forceinline__ void do_row(const CopyParams& p, int gid, int lane) {
  if (gid < 46080)      copy_row<180, 1440>(p.in2, p.o2, gid, lane);
  else if (gid < 61440) copy_row<60, 720>(p.in1, p.o1, gid - 46080, lane);
  else if (gid < 76800) copy_row<60, 720>(p.in3, p.o3, gid - 61440, lane);
  else if (gid < 84480) copy_row<30, 360>(p.in0, p.o0, gid - 76800, lane);
  else if (gid < 92160) copy_row<30, 360>(p.in4, p.o4, gid - 84480, lane);
  else                  zero_row(p, gid - 92160, lane);
}

__global__ __launch_bounds__(256, 8) void copy_kernel(CopyParams p) {
  int wid = blockIdx.x * 4 + (threadIdx.x >> 6);   // 8192 waves
  int lane = threadIdx.x & 63;
  for (int gid = wid; gid < 93184; gid += 8192) do_row(p, gid, lane);
}

extern "C" void kernel_launch(void* const* d_in, const int* in_sizes, int n_in,
                              void* d_out, int out_size, void* d_ws, size_t ws_size,
                              hipStream_t stream) {
  const float* s0 = (const float*)d_in[0];   // (256,30,360)
  const float* s1 = (const float*)d_in[1];   // (256,60,720)
  const float* s2 = (const float*)d_in[2];   // (256,180,1440)
  const float* s3 = (const float*)d_in[3];   // (256,60,720)
  const float* s4 = (const float*)d_in[4];   // (256,30,360)
  const float* wi0 = (const float*)d_in[5];  // (256,256,1,5) [ic][oc][k]
  const float* wi1 = (const float*)d_in[6];
  const float* wo0 = (const float*)d_in[7];  // (256,256,1,5) [oc][ic][k]
  const float* bo0 = (const float*)d_in[8];
  const float* wo1 = (const float*)d_in[9];
  const float* bo1 = (const float*)d_in[10];

  float* out = (float*)d_out;
  float* out0 = out;                 // (256,34,364)
  float* out1 = out + 3168256;       // (256,64,724)
  float* out2 = out + 15030272;      // (256,184,1444)
  float* out3 = out + 83048448;      // (256,64,724)
  float* out4 = out + 94910464;      // (256,34,364)

  // workspace: 4 transposed weight tables [ic][k][oc]
  float* wt0 = (float*)d_ws;
  float* wt1 = wt0 + 327680;
  float* wt2 = wt1 + 327680;
  float* wt3 = wt2 + 327680;

  WTParams wp;
  wp.src[0] = wi0; wp.src[1] = wi1; wp.src[2] = wo0; wp.src[3] = wo1;
  wp.dst[0] = wt0; wp.dst[1] = wt1; wp.dst[2] = wt2; wp.dst[3] = wt3;
  transpose_all_kernel<<<5120, 256, 0, stream>>>(wp);

  ConvParams cp;
  //           x    wt   bias    out   Hin  Win   r0  Hout Wcore h0  blk_start
  cp.j[0] = {s1, wt0, nullptr, out2,  60,  720,  58, 184, 1440,   0,   0}; // convT -> out2 top    (180 units)
  cp.j[1] = {s3, wt0, nullptr, out2,  60,  720,   0, 184, 1440, 182, 180}; // convT -> out2 bottom (180)
  cp.j[2] = {s0, wt1, nullptr, out1,  30,  360,  28,  64,  720,   0, 360}; // convT -> out1 top    ( 90)
  cp.j[3] = {s4, wt1, nullptr, out3,  30,  360,   0,  64,  720,  62, 450}; // convT -> out3 bottom ( 90)
  cp.j[4] = {s2, wt2, bo0,     out1, 180, 1440,   0,  64,  720,  62, 540}; // fwd   -> out1 bottom (180)
  cp.j[5] = {s2, wt2, bo0,     out3, 180, 1440, 178,  64,  720,   0, 720}; // fwd   -> out3 top    (180)
  cp.j[6] = {s1, wt3, bo1,     out0,  60,  720,   0,  34,  360,  32, 900}; // fwd   -> out0 bottom ( 90)
  cp.j[7] = {s3, wt3, bo1,     out4,  60,  720,  58,  34,  360,   0, 990}; // fwd   -> out4 top    ( 90)
  conv_kernel<<<1080, 256, 0, stream>>>(cp);

  CopyParams kp;
  kp.in0 = s0; kp.in1 = s1; kp.in2 = s2; kp.in3 = s3; kp.in4 = s4;
  kp.o0 = out0; kp.o1 = out1; kp.o2 = out2; kp.o3 = out3; kp.o4 = out4;
  copy_kernel<<<2048, 256, 0, stream>>>(kp);
}

// Round 8
// 322.639 us; speedup vs baseline: 1.4447x; 1.0395x over previous
//
#include <hip/hip_runtime.h>

// ---------------------------------------------------------------------------
// Earth padding of 5 strips (B=1, C=256) + edge-row cross-strip convs.
// Outputs (concatenated): (256,34,364)(256,64,724)(256,184,1444)(256,64,724)(256,34,364)
//
// Round-8: conv epilogue rewritten (round-7's ~195us conv was store-bound:
// per-thread row-strided scalar stores = 64 lines per wave-store, ~250 MB HBM
// write amplification). Now: LDS transpose -> coalesced float2 stores.
// Weights re-laid-out as [(ic/4)][k][oc][ic%4] -> 5 dwordx4 loads per chunk.
//   k1 transpose_all : builds the float4 weight tables
//   k2 conv_kernel   : 1080 blocks, one conv unit each
//   k3 copy_kernel   : unchanged (measured ~HBM ceiling in round 6)
// ---------------------------------------------------------------------------

struct ConvJob {
  const float* x; const float* wt; const float* bias; float* out;
  int Hin, Win, r0, Hout, Wcore, h0, blk_start;
};
struct ConvParams { ConvJob j[8]; };

struct CopyParams {
  const float* in0; const float* in1; const float* in2; const float* in3; const float* in4;
  float* o0; float* o1; float* o2; float* o3; float* o4;
};

struct WTParams { const float* src[4]; float* dst[4]; };

// --- weight transpose: dst[((ic/4)*5 + k)*1024 + oc*4 + (ic%4)] ---
// which 0,1: src is wi [ic][oc][1][k] ; which 2,3: src is wo [oc][ic][1][k]
__global__ __launch_bounds__(256) void transpose_all_kernel(WTParams p) {
  int b = blockIdx.x;                       // 5120 blocks = 4 * 1280
  int which = b / 1280;
  int idx = (b - which * 1280) * 256 + threadIdx.x;   // 0..327679
  int hi = idx >> 10;                       // icq*5 + k
  int icq = hi / 5;
  int k = hi - icq * 5;
  int lo = idx & 1023;
  int oc = lo >> 2;
  int icr = lo & 3;
  int ic = icq * 4 + icr;
  const float* s = p.src[which];
  float v = (which < 2) ? s[(ic * 256 + oc) * 5 + k] : s[(oc * 256 + ic) * 5 + k];
  p.dst[which][idx] = v;
}

// ---------------------------------------------------------------------------
// Conv kernel
// ---------------------------------------------------------------------------

// one conv unit. NOUT=16: circular convT (k = i+4-2cc); NOUT=8: circular fwd
// (k = cc-2i). 160 FMAs per 4-ic chunk either way.
template <int NOUT, int NCC>
__device__ __forceinline__ void conv_unit(const ConvJob jb, int local, int t, float* xs,
                                          float bv) {
  int tile = local >> 1;
  int r = local & 1;
  const int Win = jb.Win;
  const int Hout = jb.Hout;
  const float* xrow = jb.x + ((size_t)(t * jb.Hin + jb.r0 + r)) * Win;
  const float* wq = jb.wt + t * 4;          // float4 weight column for oc=t
  const int Wop = jb.Wcore + 4;
  float* orow = jb.out + ((size_t)(t * Hout + jb.h0 + r)) * Wop;

  // stage X columns into LDS: xs[cc][ic]
  int base0;
  if (NOUT == 8) base0 = 2 * (tile * 8) - 2;     // fwd: cols 2u0-2 .. 2u0+16
  else           base0 = tile * 8 - 1;           // convT: cols m0/2-1 .. m0/2+8
#pragma unroll
  for (int cc = 0; cc < NCC; ++cc) {
    int col = base0 + cc;
    col += (col < 0) ? Win : 0;
    col -= (col >= Win) ? Win : 0;
    xs[cc * 256 + t] = xrow[col];
  }
  __syncthreads();

  float acc[NOUT];
#pragma unroll
  for (int i = 0; i < NOUT; ++i) acc[i] = bv;

#pragma unroll 1
  for (int icq = 0; icq < 64; ++icq) {
    float4 wv[5];
#pragma unroll
    for (int k = 0; k < 5; ++k)
      wv[k] = *(const float4*)(wq + (size_t)(icq * 5 + k) * 1024);
    int ic0 = icq * 4;
#pragma unroll
    for (int cc = 0; cc < NCC; ++cc) {
      float4 xq = *(const float4*)&xs[cc * 256 + ic0];
#pragma unroll
      for (int i = 0; i < NOUT; ++i) {
        int k = (NOUT == 8) ? (cc - 2 * i) : (i + 4 - 2 * cc);
        if (k >= 0 && k < 5) {
          float4 w = wv[k];
          acc[i] += w.x * xq.x + w.y * xq.y + w.z * xq.z + w.w * xq.w;
        }
      }
    }
  }

  // epilogue: LDS transpose (reuse xs) -> coalesced float2 stores.
  __syncthreads();                          // all FMA reads of xs done
#pragma unroll
  for (int i = 0; i < NOUT; ++i) xs[i * 257 + t] = acc[i];   // [i][oc], pad 257
  __syncthreads();
  constexpr int SL = NOUT / 2;              // float2 slots per oc-row (8 or 4)
  constexpr int OCR = 256 / SL;             // oc-rows per round (32 or 64)
  constexpr int RND = 256 / OCR;            // rounds (8 or 4)
  int g0 = (NOUT == 8) ? tile * 8 : tile * 16;
#pragma unroll
  for (int q = 0; q < RND; ++q) {
    int oc = (t / SL) + q * OCR;
    int s = t & (SL - 1);
    float2 v = make_float2(xs[(2 * s) * 257 + oc], xs[(2 * s + 1) * 257 + oc]);
    *(float2*)(jb.out + ((size_t)(oc * Hout + jb.h0 + r)) * Wop + 2 + g0 + 2 * s) = v;
  }
  // wrap-edge duplication: first tile dups g=0,1 -> Wcore+2+g; last tile dups
  // g=Wcore-2,Wcore-1 -> 0,1. (oc = t rows; rare tiles, scalar ok)
  if (tile == 0) {
    orow[jb.Wcore + 2] = xs[0 * 257 + t];
    orow[jb.Wcore + 3] = xs[1 * 257 + t];
  }
  if (g0 + NOUT == jb.Wcore) {
    orow[0] = xs[(NOUT - 2) * 257 + t];
    orow[1] = xs[(NOUT - 1) * 257 + t];
  }
}

__global__ __launch_bounds__(256, 4) void conv_kernel(ConvParams p) {
  __shared__ float xs[19 * 256];            // 19.5 KB (X stage & transpose reuse)
  int bx = blockIdx.x;
  int t = threadIdx.x;
  if (bx < 540) {
    int ji = (bx >= 450) ? 3 : (bx >= 360) ? 2 : (bx >= 180) ? 1 : 0;
    conv_unit<16, 10>(p.j[ji], bx - p.j[ji].blk_start, t, xs, 0.f);
  } else {
    int j2 = (bx >= 990) ? 7 : (bx >= 900) ? 6 : (bx >= 720) ? 5 : 4;
    conv_unit<8, 19>(p.j[j2], bx - p.j[j2].blk_start, t, xs, p.j[j2].bias[t]);
  }
}

// ---------------------------------------------------------------------------
// Copy kernel (unchanged — measured near HBM ceiling)
// ---------------------------------------------------------------------------

__device__ __forceinline__ float4 pack4(float2 a, float2 b) {
  return make_float4(a.x, a.y, b.x, b.y);
}

template <int H, int W>
__device__ __forceinline__ void copy_row(const float* __restrict__ in,
                                         float* __restrict__ out, int rl, int lane) {
  constexpr int CORE = W / 4;               // interior float4 columns: 1..CORE-1
  int c = rl / H;
  const float* src = in + (size_t)rl * W;
  float* dst = out + (size_t)(rl + c * 4 + 2) * (W + 4);
  int w4 = 1 + lane;
  while (w4 < CORE) {
    int w4b = w4 + 64;
    float2 a0 = *(const float2*)(src + w4 * 4 - 2);
    float2 b0 = *(const float2*)(src + w4 * 4);
    if (w4b < CORE) {
      float2 a1 = *(const float2*)(src + w4b * 4 - 2);
      float2 b1 = *(const float2*)(src + w4b * 4);
      *(float4*)(dst + w4 * 4) = pack4(a0, b0);
      *(float4*)(dst + w4b * 4) = pack4(a1, b1);
    } else {
      *(float4*)(dst + w4 * 4) = pack4(a0, b0);
    }
    w4 += 128;
  }
  if (lane == 0) {
    // dst[0..3] == dst[W..W+3] == {x[W-2], x[W-1], x[0], x[1]}
    float2 E = *(const float2*)(src + W - 2);
    float2 F = *(const float2*)(src);
    float4 v = pack4(E, F);
    *(float4*)(dst) = v;
    *(float4*)(dst + W) = v;
  }
}

__device__ __forceinline__ void zero_row(const CopyParams& p, int z, int lane) {
  int strip = z >> 9, cr = z & 511, c = cr >> 1, r = cr & 1;
  float* dst = strip ? p.o4 + (size_t)(c * 34 + 32 + r) * 364
                     : p.o0 + (size_t)(c * 34 + r) * 364;
  for (int w4 = lane; w4 < 91; w4 += 64)
    *(float4*)(dst + w4 * 4) = make_float4(0.f, 0.f, 0.f, 0.f);
}

// row-job space: [0,46080) s2 | [,61440) s1 | [,76800) s3 | [,84480) s0
//                | [,92160) s4 | [,93184) zero rows
__device__ __forceinline__ void do_row(const CopyParams& p, int gid, int lane) {
  if (gid < 46080)      copy_row<180, 1440>(p.in2, p.o2, gid, lane);
  else if (gid < 61440) copy_row<60, 720>(p.in1, p.o1, gid - 46080, lane);
  else if (gid < 76800) copy_row<60, 720>(p.in3, p.o3, gid - 61440, lane);
  else if (gid < 84480) copy_row<30, 360>(p.in0, p.o0, gid - 76800, lane);
  else if (gid < 92160) copy_row<30, 360>(p.in4, p.o4, gid - 84480, lane);
  else                  zero_row(p, gid - 92160, lane);
}

__global__ __launch_bounds__(256, 8) void copy_kernel(CopyParams p) {
  int wid = blockIdx.x * 4 + (threadIdx.x >> 6);   // 8192 waves
  int lane = threadIdx.x & 63;
  for (int gid = wid; gid < 93184; gid += 8192) do_row(p, gid, lane);
}

extern "C" void kernel_launch(void* const* d_in, const int* in_sizes, int n_in,
                              void* d_out, int out_size, void* d_ws, size_t ws_size,
                              hipStream_t stream) {
  const float* s0 = (const float*)d_in[0];   // (256,30,360)
  const float* s1 = (const float*)d_in[1];   // (256,60,720)
  const float* s2 = (const float*)d_in[2];   // (256,180,1440)
  const float* s3 = (const float*)d_in[3];   // (256,60,720)
  const float* s4 = (const float*)d_in[4];   // (256,30,360)
  const float* wi0 = (const float*)d_in[5];  // (256,256,1,5) [ic][oc][k]
  const float* wi1 = (const float*)d_in[6];
  const float* wo0 = (const float*)d_in[7];  // (256,256,1,5) [oc][ic][k]
  const float* bo0 = (const float*)d_in[8];
  const float* wo1 = (const float*)d_in[9];
  const float* bo1 = (const float*)d_in[10];

  float* out = (float*)d_out;
  float* out0 = out;                 // (256,34,364)
  float* out1 = out + 3168256;       // (256,64,724)
  float* out2 = out + 15030272;      // (256,184,1444)
  float* out3 = out + 83048448;      // (256,64,724)
  float* out4 = out + 94910464;      // (256,34,364)

  // workspace: 4 float4-layout weight tables [(ic/4)][k][oc][ic%4]
  float* wt0 = (float*)d_ws;
  float* wt1 = wt0 + 327680;
  float* wt2 = wt1 + 327680;
  float* wt3 = wt2 + 327680;

  WTParams wp;
  wp.src[0] = wi0; wp.src[1] = wi1; wp.src[2] = wo0; wp.src[3] = wo1;
  wp.dst[0] = wt0; wp.dst[1] = wt1; wp.dst[2] = wt2; wp.dst[3] = wt3;
  transpose_all_kernel<<<5120, 256, 0, stream>>>(wp);

  ConvParams cp;
  //           x    wt   bias    out   Hin  Win   r0  Hout Wcore h0  blk_start
  cp.j[0] = {s1, wt0, nullptr, out2,  60,  720,  58, 184, 1440,   0,   0}; // convT -> out2 top    (180 units)
  cp.j[1] = {s3, wt0, nullptr, out2,  60,  720,   0, 184, 1440, 182, 180}; // convT -> out2 bottom (180)
  cp.j[2] = {s0, wt1, nullptr, out1,  30,  360,  28,  64,  720,   0, 360}; // convT -> out1 top    ( 90)
  cp.j[3] = {s4, wt1, nullptr, out3,  30,  360,   0,  64,  720,  62, 450}; // convT -> out3 bottom ( 90)
  cp.j[4] = {s2, wt2, bo0,     out1, 180, 1440,   0,  64,  720,  62, 540}; // fwd   -> out1 bottom (180)
  cp.j[5] = {s2, wt2, bo0,     out3, 180, 1440, 178,  64,  720,   0, 720}; // fwd   -> out3 top    (180)
  cp.j[6] = {s1, wt3, bo1,     out0,  60,  720,   0,  34,  360,  32, 900}; // fwd   -> out0 bottom ( 90)
  cp.j[7] = {s3, wt3, bo1,     out4,  60,  720,  58,  34,  360,   0, 990}; // fwd   -> out4 top    ( 90)
  conv_kernel<<<1080, 256, 0, stream>>>(cp);

  CopyParams kp;
  kp.in0 = s0; kp.in1 = s1; kp.in2 = s2; kp.in3 = s3; kp.in4 = s4;
  kp.o0 = out0; kp.o1 = out1; kp.o2 = out2; kp.o3 = out3; kp.o4 = out4;
  copy_kernel<<<2048, 256, 0, stream>>>(kp);
}